// Round 19
// baseline (295.075 us; speedup 1.0000x reference)
//
#include <hip/hip_runtime.h>
#include <math.h>

#define B 4
#define L 4096
#define D 1024
#define H 16
#define DK 64
#define M 256
#define NTOK (B*L)        // 16384
#define NCH 8
#define LC (L/NCH)        // 512
#define KVQS 3072         // row stride of fused k|v|q buffer

// dn = 64^-0.25 = 2^-1.5 ; dn^2*0.5 = 0.0625 ; ratio = 256^-0.5 = 0.0625
#define DNORM 0.35355339059327373f
#define HALF_DN2 0.0625f
#define RATIO 0.0625f

typedef _Float16 f16x8 __attribute__((ext_vector_type(8)));
typedef _Float16 f16x2 __attribute__((ext_vector_type(2)));
typedef float f32x4 __attribute__((ext_vector_type(4)));
typedef unsigned u32x4 __attribute__((ext_vector_type(4)));

// XOR-swizzled LDS index for [col][64 l] fp16 tiles: 8-half blocks permuted by col&7
#define SWZ(col, l) ((col) * 64 + (((l) & 7) | ((((((l) >> 3)) ^ (col)) & 7) << 3)))

__device__ __forceinline__ void gload16(const void* g, void* l) {
    __builtin_amdgcn_global_load_lds((const __attribute__((address_space(1))) unsigned*)g,
                                     (__attribute__((address_space(3))) unsigned*)l, 16, 0, 0);
}

// ---------------- merged casts: X (blocks 0..8191), W4 (8192..10239), P-frag (10240) ----------------
__global__ __launch_bounds__(256) void cast_all(const float* __restrict__ X,
                                                const float* __restrict__ Wk,
                                                const float* __restrict__ Wv,
                                                const float* __restrict__ Wq,
                                                const float* __restrict__ Wo,
                                                const float* __restrict__ P,
                                                _Float16* __restrict__ Xh,
                                                _Float16* __restrict__ Wall,
                                                _Float16* __restrict__ Phf) {
    const int blk = blockIdx.x;
    const int t = threadIdx.x;
    if (blk < 8192) {
        const int i = blk * 256 + t;
        const float4* p = (const float4*)(X + (size_t)i * 8);
        float4 a = p[0], b = p[1];
        f16x8 o;
        o[0] = (_Float16)a.x; o[1] = (_Float16)a.y; o[2] = (_Float16)a.z; o[3] = (_Float16)a.w;
        o[4] = (_Float16)b.x; o[5] = (_Float16)b.y; o[6] = (_Float16)b.z; o[7] = (_Float16)b.w;
        *(f16x8*)(Xh + (size_t)i * 8) = o;
    } else if (blk < 10240) {
        const int j = (blk - 8192) * 256 + t;     // < 524288
        const int y = j >> 17, i = j & 131071;
        const float* src = (y == 0) ? Wk : (y == 1) ? Wv : (y == 2) ? Wq : Wo;
        const float4* p = (const float4*)(src + (size_t)i * 8);
        float4 a = p[0], b = p[1];
        f16x8 o;
        o[0] = (_Float16)a.x; o[1] = (_Float16)a.y; o[2] = (_Float16)a.z; o[3] = (_Float16)a.w;
        o[4] = (_Float16)b.x; o[5] = (_Float16)b.y; o[6] = (_Float16)b.z; o[7] = (_Float16)b.w;
        *(f16x8*)(Wall + (size_t)y * 1048576 + (size_t)i * 8) = o;
    } else {
#pragma unroll
        for (int ii = 0; ii < 8; ii++) {
            const int c = t + ii * 256;
            const int f = c >> 6, lane2 = c & 63;
            const int nf = f >> 1, kh = f & 1;
            const int fr = lane2 & 15, kq2 = lane2 >> 4;
            const float* src = P + (nf * 16 + fr) * 64 + kh * 32 + kq2 * 8;
            f16x8 o;
#pragma unroll
            for (int j = 0; j < 8; j++) o[j] = (_Float16)src[j];
            *(f16x8*)(Phf + (size_t)c * 8) = o;
        }
    }
}

// ---------------- 256x256 counted-vmcnt fp16 MFMA GEMM, BK=64, 2 barriers per K-tile ----------------
// (r14/r16 proven structure) C[n][o] = sum_k A[n][k] * W[o][k].  512 threads = 8 waves (2Mx4N),
// double-buffered LDS (128KB), chunk-XOR swizzle. Waves free-run within a tile;
// explicit lgkmcnt(0)+memory-clobber before each barrier. vmcnt(2) never 0 in loop.
template <typename CT>
__global__ __launch_bounds__(512) void gemm256(const _Float16* __restrict__ A,
                                               const _Float16* __restrict__ W,
                                               CT* __restrict__ C,
                                               int N, int K) {
    __shared__ _Float16 As[2][256 * 64];
    __shared__ _Float16 Bs[2][256 * 64];
    const int t = threadIdx.x;
    const int lane = t & 63;
    const int wid = t >> 6;
    const int wr = wid >> 2, wc = wid & 3;
    const int fr = lane & 15, kq = lane >> 4;

    const int nwg = gridDim.x * gridDim.y;
    int lid = blockIdx.y * gridDim.x + blockIdx.x;
    lid = (lid & 7) * (nwg >> 3) + (lid >> 3);      // bijective XCD chunking (nwg%8==0)
    const int bx = lid % gridDim.x, by = lid / gridDim.x;
    const int brow = by * 256, bcol = bx * 256;

    const int nt = K >> 6;

    f32x4 acc[8][4];
#pragma unroll
    for (int i = 0; i < 8; i++)
#pragma unroll
        for (int j = 0; j < 4; j++) acc[i][j] = (f32x4){0.f, 0.f, 0.f, 0.f};

    f16x8 af[4][2], bf[4][2];

#define STAGE_PAIR(buf_, k0_, j_) { \
    const int c_ = (j_) * 512 + t; \
    const int srow_ = c_ >> 3; \
    const int src_ = (c_ & 7) ^ (srow_ & 7); \
    gload16(A + (size_t)(brow + srow_) * K + (k0_) + src_ * 8, &As[buf_][c_ * 8]); \
    gload16(W + (size_t)(bcol + srow_) * K + (k0_) + src_ * 8, &Bs[buf_][c_ * 8]); }

#define READ_A(buf_, mh_) { \
    _Pragma("unroll") \
    for (int mi = 0; mi < 4; mi++) { \
        const int row_ = wr * 128 + (mh_) * 64 + mi * 16 + fr; \
        af[mi][0] = *(const f16x8*)&As[buf_][row_ * 64 + ((kq ^ (row_ & 7)) << 3)]; \
        af[mi][1] = *(const f16x8*)&As[buf_][row_ * 64 + (((4 + kq) ^ (row_ & 7)) << 3)]; \
    } }

#define READ_B2(buf_, nh_) { \
    _Pragma("unroll") \
    for (int ni = 0; ni < 2; ni++) { \
        const int row_ = wc * 64 + ((nh_) * 2 + ni) * 16 + fr; \
        bf[(nh_) * 2 + ni][0] = *(const f16x8*)&Bs[buf_][row_ * 64 + ((kq ^ (row_ & 7)) << 3)]; \
        bf[(nh_) * 2 + ni][1] = *(const f16x8*)&Bs[buf_][row_ * 64 + (((4 + kq) ^ (row_ & 7)) << 3)]; \
    } }

#define MFMA_Q(mh_, nh_) { \
    _Pragma("unroll") \
    for (int mi = 0; mi < 4; mi++) \
        _Pragma("unroll") \
        for (int ni = 0; ni < 2; ni++) { \
            acc[(mh_) * 4 + mi][(nh_) * 2 + ni] = __builtin_amdgcn_mfma_f32_16x16x32_f16( \
                af[mi][0], bf[(nh_) * 2 + ni][0], acc[(mh_) * 4 + mi][(nh_) * 2 + ni], 0, 0, 0); \
            acc[(mh_) * 4 + mi][(nh_) * 2 + ni] = __builtin_amdgcn_mfma_f32_16x16x32_f16( \
                af[mi][1], bf[(nh_) * 2 + ni][1], acc[(mh_) * 4 + mi][(nh_) * 2 + ni], 0, 0, 0); \
        } }

#define FENCE_LGKM { asm volatile("s_waitcnt lgkmcnt(0)" ::: "memory"); }
#define WAIT_VM2   { asm volatile("s_waitcnt vmcnt(2)" ::: "memory"); }
#define BAR __builtin_amdgcn_s_barrier()

    // prologue: tile0 pairs 0-3, tile1 pair0; validate buf0 keeping 2 loads in flight
    STAGE_PAIR(0, 0, 0);
    STAGE_PAIR(0, 0, 1);
    STAGE_PAIR(0, 0, 2);
    STAGE_PAIR(0, 0, 3);
    STAGE_PAIR(1, (nt > 1 ? 64 : 0), 0);
    WAIT_VM2; BAR;

    for (int tau = 0; tau < nt; ++tau) {
        const int cur = tau & 1, nxt = cur ^ 1;
        const int k1 = (tau + 1 < nt) ? (tau + 1) * 64 : 0;   // clamp: garbage into unread buf
        const int k2 = (tau + 2 < nt) ? (tau + 2) * 64 : 0;

        // free-run region: reads + staging + 3 MFMA quadrants, compiler-scheduled
        READ_A(cur, 0);
        READ_B2(cur, 0);
        STAGE_PAIR(nxt, k1, 1);
        STAGE_PAIR(nxt, k1, 2);
        STAGE_PAIR(nxt, k1, 3);
        __builtin_amdgcn_s_setprio(1); MFMA_Q(0, 0); __builtin_amdgcn_s_setprio(0);
        READ_B2(cur, 1);
        __builtin_amdgcn_s_setprio(1); MFMA_Q(0, 1); __builtin_amdgcn_s_setprio(0);
        READ_A(cur, 1);
        __builtin_amdgcn_s_setprio(1); MFMA_Q(1, 0); __builtin_amdgcn_s_setprio(0);

        // all cur reads retired (lgkm=0) before any wave overwrites cur p0 below
        FENCE_LGKM; BAR;

        __builtin_amdgcn_s_setprio(1); MFMA_Q(1, 1); __builtin_amdgcn_s_setprio(0);
        STAGE_PAIR(cur, k2, 0);   // tau+2 p0 into rows 0-63 (disjoint from pending row-64+ reads)
        WAIT_VM2; FENCE_LGKM; BAR;  // retires nxt p0..p3 (queue: [nxt p0..p3, cur p0])
    }
    asm volatile("s_waitcnt vmcnt(0)" ::: "memory");

    // epilogue: C layout col=lane&15, row=(lane>>4)*4+reg
#pragma unroll
    for (int mi = 0; mi < 8; mi++)
#pragma unroll
        for (int ni = 0; ni < 4; ni++) {
            const int row = brow + wr * 128 + mi * 16 + kq * 4;
            const int col = bcol + wc * 64 + ni * 16 + fr;
#pragma unroll
            for (int r = 0; r < 4; r++)
                C[(size_t)(row + r) * N + col] = (CT)acc[mi][ni][r];
        }
#undef STAGE_PAIR
#undef READ_A
#undef READ_B2
#undef MFMA_Q
#undef FENCE_LGKM
#undef WAIT_VM2
#undef BAR
}

// ---------------- MFMA phi_k + kv/ksum partials; T14 register prefetch of next tile's k/v ----------------
// k/v/q interleaved in kvq: row stride 3072, k at +0, v at +1024. LDS 42KB.
__global__ __launch_bounds__(256) void kv_kernel4(const _Float16* __restrict__ kvq,
                                                  const int* __restrict__ mask,
                                                  const _Float16* __restrict__ Phf,
                                                  float* __restrict__ kvpart,
                                                  float* __restrict__ kspart) {
    const int bh = blockIdx.y, b = bh >> 4, h = bh & 15;
    const int ch = blockIdx.x;
    const int t = threadIdx.x, lane = t & 63, w = t >> 6;
    const int fr = lane & 15, kq = lane >> 4;

    __shared__ _Float16 phis[256 * 64];   // [m][l] swizzled          32KB
    __shared__ _Float16 vst[80 * 64];     // [d][l] swizzled; row64=1 10KB

    if (t < 128) {
        const int row = 64 + (t >> 3), off = (t & 7) * 8;
        const _Float16 val = (row == 64) ? (_Float16)1.0f : (_Float16)0.0f;
        f16x8 o = {val, val, val, val, val, val, val, val};
        *(f16x8*)&vst[row * 64 + off] = o;
    }
    __syncthreads();

    f32x4 acc[4][5];
#pragma unroll
    for (int mf = 0; mf < 4; mf++)
#pragma unroll
        for (int n2 = 0; n2 < 5; n2++) acc[mf][n2] = (f32x4){0.f, 0.f, 0.f, 0.f};

    const int rr = t & 31, seg = t >> 5;
    const int NT = LC / 64;

    // T14: preload tile 0's k/v into registers
    f16x8 pv0, pv1, pk0, pk1;
    {
        const int l0 = ch * LC;
        const _Float16* v0 = kvq + (size_t)(b * L + l0 + 2 * rr) * KVQS + 1024 + h * DK + seg * 8;
        pv0 = *(const f16x8*)v0;
        pv1 = *(const f16x8*)(v0 + KVQS);
        const _Float16* krow = kvq + (size_t)(b * L + l0 + w * 16 + fr) * KVQS + h * DK + kq * 8;
        pk0 = *(const f16x8*)krow;
        pk1 = *(const f16x8*)(krow + 32);
    }

    for (int tile = 0; tile < NT; ++tile) {
        const int l0 = ch * LC + tile * 64;

        // consume current registers
        f16x8 va0 = pv0, va1 = pv1;
        f16x8 ak0 = pk0, ak1 = pk1;

        // issue next tile's loads immediately (clamped to tile 0; values unused on last iter)
        {
            const int ln = ch * LC + ((tile + 1 < NT) ? (tile + 1) * 64 : 0);
            const _Float16* v0 = kvq + (size_t)(b * L + ln + 2 * rr) * KVQS + 1024 + h * DK + seg * 8;
            pv0 = *(const f16x8*)v0;
            pv1 = *(const f16x8*)(v0 + KVQS);
            const _Float16* krow = kvq + (size_t)(b * L + ln + w * 16 + fr) * KVQS + h * DK + kq * 8;
            pk0 = *(const f16x8*)krow;
            pk1 = *(const f16x8*)(krow + 32);
        }

        // stage v transposed into vst (from current regs)
#pragma unroll
        for (int j = 0; j < 8; j++) {
            const int d = seg * 8 + j;
            f16x2 pk = {va0[j], va1[j]};
            *(f16x2*)&vst[SWZ(d, 2 * rr)] = pk;
        }

        float ns = 0.f;
#pragma unroll
        for (int j = 0; j < 8; j++)
            ns += (float)ak0[j] * (float)ak0[j] + (float)ak1[j] * (float)ak1[j];
        ns += __shfl_xor(ns, 16);
        ns += __shfl_xor(ns, 32);
        ns *= HALF_DN2;

        f32x4 pr[16];
#pragma unroll
        for (int nf = 0; nf < 16; nf++) {
            f16x8 b0 = *(const f16x8*)&Phf[((size_t)(nf * 2 + 0) * 64 + lane) * 8];
            f16x8 b1 = *(const f16x8*)&Phf[((size_t)(nf * 2 + 1) * 64 + lane) * 8];
            f32x4 c = {0.f, 0.f, 0.f, 0.f};
            c = __builtin_amdgcn_mfma_f32_16x16x32_f16(ak0, b0, c, 0, 0, 0);
            c = __builtin_amdgcn_mfma_f32_16x16x32_f16(ak1, b1, c, 0, 0, 0);
            pr[nf] = c;
        }
        float mx[4] = {-1e30f, -1e30f, -1e30f, -1e30f};
#pragma unroll
        for (int nf = 0; nf < 16; nf++)
#pragma unroll
            for (int r = 0; r < 4; r++) {
                pr[nf][r] *= DNORM;
                mx[r] = fmaxf(mx[r], pr[nf][r]);
            }
#pragma unroll
        for (int r = 0; r < 4; r++) {
            mx[r] = fmaxf(mx[r], __shfl_xor(mx[r], 1));
            mx[r] = fmaxf(mx[r], __shfl_xor(mx[r], 2));
            mx[r] = fmaxf(mx[r], __shfl_xor(mx[r], 4));
            mx[r] = fmaxf(mx[r], __shfl_xor(mx[r], 8));
        }
        float sub[4], mkv[4];
#pragma unroll
        for (int r = 0; r < 4; r++) {
            sub[r] = mx[r] + __shfl(ns, kq * 4 + r);
            mkv[r] = (float)mask[b * L + l0 + w * 16 + kq * 4 + r];
        }
#pragma unroll
        for (int nf = 0; nf < 16; nf++) {
            const int col = nf * 16 + fr;
#pragma unroll
            for (int rp = 0; rp < 2; rp++) {
                const int row = w * 16 + kq * 4 + 2 * rp;
                float v0 = mkv[2 * rp]     * (RATIO * (__expf(pr[nf][2 * rp]     - sub[2 * rp])     + 1e-6f));
                float v1 = mkv[2 * rp + 1] * (RATIO * (__expf(pr[nf][2 * rp + 1] - sub[2 * rp + 1]) + 1e-6f));
                f16x2 pk = {(_Float16)v0, (_Float16)v1};
                *(f16x2*)&phis[SWZ(col, row)] = pk;
            }
        }
        __syncthreads();

        f16x8 bfr[5][2];
#pragma unroll
        for (int n2 = 0; n2 < 5; n2++)
#pragma unroll
            for (int ks = 0; ks < 2; ks++)
                bfr[n2][ks] = *(const f16x8*)&vst[SWZ(n2 * 16 + fr, ks * 32 + kq * 8)];
#pragma unroll
        for (int mf = 0; mf < 4; mf++) {
            const int m = w * 64 + mf * 16 + fr;
            f16x8 a0 = *(const f16x8*)&phis[SWZ(m, kq * 8)];
            f16x8 a1 = *(const f16x8*)&phis[SWZ(m, 32 + kq * 8)];
#pragma unroll
            for (int n2 = 0; n2 < 5; n2++) {
                acc[mf][n2] = __builtin_amdgcn_mfma_f32_16x16x32_f16(a0, bfr[n2][0], acc[mf][n2], 0, 0, 0);
                acc[mf][n2] = __builtin_amdgcn_mfma_f32_16x16x32_f16(a1, bfr[n2][1], acc[mf][n2], 0, 0, 0);
            }
        }
        __syncthreads();
    }

    float* kvp = kvpart + ((size_t)ch * 64 + bh) * M * DK;
    float* ksp = kspart + ((size_t)ch * 64 + bh) * M;
#pragma unroll
    for (int mf = 0; mf < 4; mf++) {
#pragma unroll
        for (int r = 0; r < 4; r++) {
            const int m = w * 64 + mf * 16 + kq * 4 + r;
#pragma unroll
            for (int n2 = 0; n2 < 4; n2++)
                kvp[(size_t)m * DK + n2 * 16 + fr] = acc[mf][n2][r];
            if (fr == 0) ksp[m] = acc[mf][4][r];
        }
    }
}

// ---------------- reduce partials -> kvt fp16 FRAGMENT-LINEAR ----------------
__global__ __launch_bounds__(256) void reduce_kvt2(const float* __restrict__ kvp,
                                                   const float* __restrict__ ksp,
                                                   _Float16* __restrict__ kvt) {
    const int dq = blockIdx.x, bh = blockIdx.y;
    const int t  = threadIdx.x;   // m index
    float s[16];
#pragma unroll
    for (int c = 0; c < 16; c++) s[c] = 0.f;
    for (int ch = 0; ch < NCH; ch++) {
        const float* src = kvp + (((size_t)ch * 64 + bh) * M + t) * DK + dq * 16;
#pragma unroll
        for (int c4 = 0; c4 < 4; c4++) {
            float4 v = *(const float4*)(src + c4 * 4);
            s[c4 * 4 + 0] += v.x; s[c4 * 4 + 1] += v.y;
            s[c4 * 4 + 2] += v.z; s[c4 * 4 + 3] += v.w;
        }
    }
    _Float16* dst = kvt + (size_t)bh * 20480;
    const int ks = t >> 5, kq = (t >> 3) & 3, j = t & 7;
#pragma unroll
    for (int c = 0; c < 16; c++)
        dst[((dq * 8 + ks) * 64 + kq * 16 + c) * 8 + j] = (_Float16)s[c];
    if (dq == 0) {
        float s64 = 0.f;
        for (int ch = 0; ch < NCH; ch++) s64 += ksp[((size_t)ch * 64 + bh) * M + t];
        dst[((4 * 8 + ks) * 64 + kq * 16 + 0) * 8 + j] = (_Float16)s64;
#pragma unroll
        for (int c = 1; c < 16; c++)
            dst[((4 * 8 + ks) * 64 + kq * 16 + c) * 8 + j] = (_Float16)0.f;
    }
}

// ---------------- phi_q + out + denom + normalize; swapped QK, register butterfly ----------------
// q = kvq + 2048 (row stride KVQS). grid (L/64, B*H) = 4096 blocks, bijective XCD swizzle.
__global__ __launch_bounds__(256) void out_kernel8(const _Float16* __restrict__ q,
                                                   const _Float16* __restrict__ Phf,
                                                   const _Float16* __restrict__ kvtf,
                                                   _Float16* __restrict__ ao) {
    const int nwg = gridDim.x * gridDim.y;               // 4096
    int lid = blockIdx.y * gridDim.x + blockIdx.x;
    lid = (lid & 7) * (nwg >> 3) + (lid >> 3);           // bijective XCD chunking
    const int bh = lid >> 6, lblk = lid & 63;
    const int b = bh >> 4, h = bh & 15;
    const int l0 = lblk * 64;
    const int t = threadIdx.x, lane = t & 63, w = t >> 6;
    const int fr = lane & 15, kq = lane >> 4;

    __shared__ _Float16 kvs[2560 * 8];    // fragment-linear kvt  40KB

    {
        const _Float16* src = kvtf + (size_t)bh * 20480 + t * 8;
#pragma unroll
        for (int i = 0; i < 10; i++)
            gload16(src + i * 2048, kvs + t * 8 + i * 2048);
    }

    const int srcA = fr + 16 * ((2 * kq) & 3);
    const int srcB = fr + 16 * ((2 * kq + 1) & 3);
    const bool hi  = (kq & 2) != 0;

    const _Float16* qp = q + (size_t)(b * L + l0 + w * 16 + fr) * KVQS + h * DK + kq * 8;
    f16x8 aq0 = *(const f16x8*)qp;
    f16x8 aq1 = *(const f16x8*)(qp + 32);
    float ns = 0.f;
#pragma unroll
    for (int j = 0; j < 8; j++)
        ns += (float)aq0[j] * (float)aq0[j] + (float)aq1[j] * (float)aq1[j];
    ns += __shfl_xor(ns, 16);
    ns += __shfl_xor(ns, 32);
    ns *= HALF_DN2;

    f32x4 pr[16];
#pragma unroll
    for (int nf = 0; nf < 16; nf++) {
        f16x8 a0 = *(const f16x8*)&Phf[((size_t)(nf * 2 + 0) * 64 + lane) * 8];
        f16x8 a1 = *(const f16x8*)&Phf[((size_t)(nf * 2 + 1) * 64 + lane) * 8];
        f32x4 c = {0.f, 0.f, 0.f, 0.f};
        c = __builtin_amdgcn_mfma_f32_16x16x32_f16(a0, aq0, c, 0, 0, 0);
        c = __builtin_amdgcn_mfma_f32_16x16x32_f16(a1, aq1, c, 0, 0, 0);
        pr[nf] = c;
    }
    float mx = -1e30f;
#pragma unroll
    for (int nf = 0; nf < 16; nf++)
#pragma unroll
        for (int r = 0; r < 4; r++) {
            pr[nf][r] *= DNORM;
            mx = fmaxf(mx, pr[nf][r]);
        }
    mx = fmaxf(mx, __shfl_xor(mx, 16));
    mx = fmaxf(mx, __shfl_xor(mx, 32));
    const float sub = mx + ns;

    unsigned pk_[16][2];
#pragma unroll
    for (int nf = 0; nf < 16; nf++) {
#pragma unroll
        for (int p = 0; p < 2; p++) {
            float v0 = RATIO * (__expf(pr[nf][2 * p]     - sub) + 1e-6f);
            float v1 = RATIO * (__expf(pr[nf][2 * p + 1] - sub) + 1e-6f);
            f16x2 pq = {(_Float16)v0, (_Float16)v1};
            pk_[nf][p] = __builtin_bit_cast(unsigned, pq);
        }
    }
    __syncthreads();   // kvs staged (drains vmcnt; hidden under phase 1)

    f32x4 acc[5];
#pragma unroll
    for (int n2 = 0; n2 < 5; n2++) acc[n2] = (f32x4){0.f, 0.f, 0.f, 0.f};
#pragma unroll
    for (int ks = 0; ks < 8; ks++) {
        unsigned u0 = __shfl(pk_[2 * ks][0], srcA);
        unsigned u1 = __shfl(pk_[2 * ks][1], srcA);
        unsigned u2 = __shfl(pk_[2 * ks][0], srcB);
        unsigned u3 = __shfl(pk_[2 * ks][1], srcB);
        unsigned v0 = __shfl(pk_[2 * ks + 1][0], srcA);
        unsigned v1 = __shfl(pk_[2 * ks + 1][1], srcA);
        unsigned v2 = __shfl(pk_[2 * ks + 1][0], srcB);
        unsigned v3 = __shfl(pk_[2 * ks + 1][1], srcB);
        u32x4 wv;
        wv[0] = hi ? v0 : u0;
        wv[1] = hi ? v1 : u1;
        wv[2] = hi ? v2 : u2;
        wv[3] = hi ? v3 : u3;
        f16x8 af = __builtin_bit_cast(f16x8, wv);
#pragma unroll
        for (int n2 = 0; n2 < 5; n2++) {
            f16x8 bfv = *(const f16x8*)&kvs[((n2 * 8 + ks) * 64 + lane) * 8];
            acc[n2] = __builtin_amdgcn_mfma_f32_16x16x32_f16(af, bfv, acc[n2], 0, 0, 0);
        }
    }
#pragma unroll
    for (int r = 0; r < 4; r++) {
        float den = __shfl(acc[4][r], (lane & 48));
        float inv = 1.f / fmaxf(den, 1e-6f);
        const int row = l0 + w * 16 + kq * 4 + r;
        _Float16* dst = ao + (size_t)(b * L + row) * D + h * DK;
#pragma unroll
        for (int n2 = 0; n2 < 4; n2++)
            dst[n2 * 16 + fr] = (_Float16)(acc[n2][r] * inv);
    }
}

extern "C" void kernel_launch(void* const* d_in, const int* in_sizes, int n_in,
                              void* d_out, int out_size, void* d_ws, size_t ws_size,
                              hipStream_t stream) {
    (void)in_sizes; (void)n_in; (void)out_size; (void)ws_size;
    const float* X    = (const float*)d_in[0];
    const int*   mask = (const int*)d_in[1];
    const float* Wq   = (const float*)d_in[2];
    const float* Wk   = (const float*)d_in[3];
    const float* Wv   = (const float*)d_in[4];
    const float* Wo   = (const float*)d_in[5];
    const float* P    = (const float*)d_in[6];

    char* ws = (char*)d_ws;
    // slot0 (32MB) serially hosts Xh -> kvpart -> attn (lifetimes disjoint by kernel order)
    _Float16* Xh    = (_Float16*)ws;                      // castX..gemmKVQ
    float* kvpart   = (float*)ws;                         // kv_kernel4..reduce
    _Float16* attn  = (_Float16*)ws;                      // out_kernel8..gemmO
    _Float16* kvq   = (_Float16*)(ws + 33554432);         // 96MB [k|v|q] stride 3072
    float* kspart   = (float*)(ws + 134217728);           // 512KB
    _Float16* kvt   = (_Float16*)(ws + 134742016);        // 2.62MB
    _Float16* Wall  = (_Float16*)(ws + 137363456);        // 8MB [Wk;Wv;Wq;Wo]
    _Float16* Phf   = (_Float16*)(ws + 145752064);        // 32KB -> extent 145.8MB (proven)
    float* out      = (float*)d_out;

    dim3 blk(256);
    hipLaunchKernelGGL(cast_all, dim3(10241), blk, 0, stream, X, Wk, Wv, Wq, Wo, P, Xh, Wall, Phf);

    // Fused K+V+Q projection: C[16384][3072] = Xh @ [Wk;Wv;Wq]^T
    hipLaunchKernelGGL((gemm256<_Float16>), dim3(12, 64), dim3(512), 0, stream, Xh, Wall, kvq, KVQS, D);

    hipLaunchKernelGGL(kv_kernel4, dim3(NCH, B * H), blk, 0, stream, kvq, mask, Phf, kvpart, kspart);
    hipLaunchKernelGGL(reduce_kvt2, dim3(4, 64), blk, 0, stream, kvpart, kspart, kvt);

    hipLaunchKernelGGL(out_kernel8, dim3(L / 64, B * H), blk, 0, stream, kvq + 2048, Phf, kvt, attn);

    hipLaunchKernelGGL((gemm256<float>), dim3(4, 64), dim3(512), 0, stream, attn, Wall + 3 * 1048576, out, D, D);
}

// Round 20
// 277.581 us; speedup vs baseline: 1.0630x; 1.0630x over previous
//
#include <hip/hip_runtime.h>
#include <math.h>

#define B 4
#define L 4096
#define D 1024
#define H 16
#define DK 64
#define M 256
#define NTOK (B*L)        // 16384
#define NCH 8
#define LC (L/NCH)        // 512
#define KVQS 3072         // row stride of fused k|v|q buffer

// dn = 64^-0.25 = 2^-1.5 ; dn^2*0.5 = 0.0625 ; ratio = 256^-0.5 = 0.0625
#define DNORM 0.35355339059327373f
#define HALF_DN2 0.0625f
#define RATIO 0.0625f

typedef _Float16 f16x8 __attribute__((ext_vector_type(8)));
typedef _Float16 f16x2 __attribute__((ext_vector_type(2)));
typedef float f32x4 __attribute__((ext_vector_type(4)));
typedef unsigned u32x4 __attribute__((ext_vector_type(4)));

// XOR-swizzled LDS index for [col][64 l] fp16 tiles: 8-half blocks permuted by col&7
#define SWZ(col, l) ((col) * 64 + (((l) & 7) | ((((((l) >> 3)) ^ (col)) & 7) << 3)))

__device__ __forceinline__ void gload16(const void* g, void* l) {
    __builtin_amdgcn_global_load_lds((const __attribute__((address_space(1))) unsigned*)g,
                                     (__attribute__((address_space(3))) unsigned*)l, 16, 0, 0);
}

// ---------------- merged casts: X (blocks 0..8191), W4 (8192..10239), P-frag (10240) ----------------
__global__ __launch_bounds__(256) void cast_all(const float* __restrict__ X,
                                                const float* __restrict__ Wk,
                                                const float* __restrict__ Wv,
                                                const float* __restrict__ Wq,
                                                const float* __restrict__ Wo,
                                                const float* __restrict__ P,
                                                _Float16* __restrict__ Xh,
                                                _Float16* __restrict__ Wall,
                                                _Float16* __restrict__ Phf) {
    const int blk = blockIdx.x;
    const int t = threadIdx.x;
    if (blk < 8192) {
        const int i = blk * 256 + t;
        const float4* p = (const float4*)(X + (size_t)i * 8);
        float4 a = p[0], b = p[1];
        f16x8 o;
        o[0] = (_Float16)a.x; o[1] = (_Float16)a.y; o[2] = (_Float16)a.z; o[3] = (_Float16)a.w;
        o[4] = (_Float16)b.x; o[5] = (_Float16)b.y; o[6] = (_Float16)b.z; o[7] = (_Float16)b.w;
        *(f16x8*)(Xh + (size_t)i * 8) = o;
    } else if (blk < 10240) {
        const int j = (blk - 8192) * 256 + t;     // < 524288
        const int y = j >> 17, i = j & 131071;
        const float* src = (y == 0) ? Wk : (y == 1) ? Wv : (y == 2) ? Wq : Wo;
        const float4* p = (const float4*)(src + (size_t)i * 8);
        float4 a = p[0], b = p[1];
        f16x8 o;
        o[0] = (_Float16)a.x; o[1] = (_Float16)a.y; o[2] = (_Float16)a.z; o[3] = (_Float16)a.w;
        o[4] = (_Float16)b.x; o[5] = (_Float16)b.y; o[6] = (_Float16)b.z; o[7] = (_Float16)b.w;
        *(f16x8*)(Wall + (size_t)y * 1048576 + (size_t)i * 8) = o;
    } else {
#pragma unroll
        for (int ii = 0; ii < 8; ii++) {
            const int c = t + ii * 256;
            const int f = c >> 6, lane2 = c & 63;
            const int nf = f >> 1, kh = f & 1;
            const int fr = lane2 & 15, kq2 = lane2 >> 4;
            const float* src = P + (nf * 16 + fr) * 64 + kh * 32 + kq2 * 8;
            f16x8 o;
#pragma unroll
            for (int j = 0; j < 8; j++) o[j] = (_Float16)src[j];
            *(f16x8*)(Phf + (size_t)c * 8) = o;
        }
    }
}

// ---------------- 256x256 counted-vmcnt fp16 MFMA GEMM, BK=64, 2 barriers per K-tile ----------------
// (proven structure) C[n][o] = sum_k A[n][k] * W[o][k].  512 threads = 8 waves (2Mx4N),
// double-buffered LDS (128KB), chunk-XOR swizzle. Waves free-run within a tile;
// explicit lgkmcnt(0)+memory-clobber before each barrier. vmcnt(2) never 0 in loop.
template <typename CT>
__global__ __launch_bounds__(512) void gemm256(const _Float16* __restrict__ A,
                                               const _Float16* __restrict__ W,
                                               CT* __restrict__ C,
                                               int N, int K) {
    __shared__ _Float16 As[2][256 * 64];
    __shared__ _Float16 Bs[2][256 * 64];
    const int t = threadIdx.x;
    const int lane = t & 63;
    const int wid = t >> 6;
    const int wr = wid >> 2, wc = wid & 3;
    const int fr = lane & 15, kq = lane >> 4;

    const int nwg = gridDim.x * gridDim.y;
    int lid = blockIdx.y * gridDim.x + blockIdx.x;
    lid = (lid & 7) * (nwg >> 3) + (lid >> 3);      // bijective XCD chunking (nwg%8==0)
    const int bx = lid % gridDim.x, by = lid / gridDim.x;
    const int brow = by * 256, bcol = bx * 256;

    const int nt = K >> 6;

    f32x4 acc[8][4];
#pragma unroll
    for (int i = 0; i < 8; i++)
#pragma unroll
        for (int j = 0; j < 4; j++) acc[i][j] = (f32x4){0.f, 0.f, 0.f, 0.f};

    f16x8 af[4][2], bf[4][2];

#define STAGE_PAIR(buf_, k0_, j_) { \
    const int c_ = (j_) * 512 + t; \
    const int srow_ = c_ >> 3; \
    const int src_ = (c_ & 7) ^ (srow_ & 7); \
    gload16(A + (size_t)(brow + srow_) * K + (k0_) + src_ * 8, &As[buf_][c_ * 8]); \
    gload16(W + (size_t)(bcol + srow_) * K + (k0_) + src_ * 8, &Bs[buf_][c_ * 8]); }

#define READ_A(buf_, mh_) { \
    _Pragma("unroll") \
    for (int mi = 0; mi < 4; mi++) { \
        const int row_ = wr * 128 + (mh_) * 64 + mi * 16 + fr; \
        af[mi][0] = *(const f16x8*)&As[buf_][row_ * 64 + ((kq ^ (row_ & 7)) << 3)]; \
        af[mi][1] = *(const f16x8*)&As[buf_][row_ * 64 + (((4 + kq) ^ (row_ & 7)) << 3)]; \
    } }

#define READ_B2(buf_, nh_) { \
    _Pragma("unroll") \
    for (int ni = 0; ni < 2; ni++) { \
        const int row_ = wc * 64 + ((nh_) * 2 + ni) * 16 + fr; \
        bf[(nh_) * 2 + ni][0] = *(const f16x8*)&Bs[buf_][row_ * 64 + ((kq ^ (row_ & 7)) << 3)]; \
        bf[(nh_) * 2 + ni][1] = *(const f16x8*)&Bs[buf_][row_ * 64 + (((4 + kq) ^ (row_ & 7)) << 3)]; \
    } }

#define MFMA_Q(mh_, nh_) { \
    _Pragma("unroll") \
    for (int mi = 0; mi < 4; mi++) \
        _Pragma("unroll") \
        for (int ni = 0; ni < 2; ni++) { \
            acc[(mh_) * 4 + mi][(nh_) * 2 + ni] = __builtin_amdgcn_mfma_f32_16x16x32_f16( \
                af[mi][0], bf[(nh_) * 2 + ni][0], acc[(mh_) * 4 + mi][(nh_) * 2 + ni], 0, 0, 0); \
            acc[(mh_) * 4 + mi][(nh_) * 2 + ni] = __builtin_amdgcn_mfma_f32_16x16x32_f16( \
                af[mi][1], bf[(nh_) * 2 + ni][1], acc[(mh_) * 4 + mi][(nh_) * 2 + ni], 0, 0, 0); \
        } }

#define FENCE_LGKM { asm volatile("s_waitcnt lgkmcnt(0)" ::: "memory"); }
#define WAIT_VM2   { asm volatile("s_waitcnt vmcnt(2)" ::: "memory"); }
#define BAR __builtin_amdgcn_s_barrier()

    // prologue: tile0 pairs 0-3, tile1 pair0; validate buf0 keeping 2 loads in flight
    STAGE_PAIR(0, 0, 0);
    STAGE_PAIR(0, 0, 1);
    STAGE_PAIR(0, 0, 2);
    STAGE_PAIR(0, 0, 3);
    STAGE_PAIR(1, (nt > 1 ? 64 : 0), 0);
    WAIT_VM2; BAR;

    for (int tau = 0; tau < nt; ++tau) {
        const int cur = tau & 1, nxt = cur ^ 1;
        const int k1 = (tau + 1 < nt) ? (tau + 1) * 64 : 0;   // clamp: garbage into unread buf
        const int k2 = (tau + 2 < nt) ? (tau + 2) * 64 : 0;

        // free-run region: reads + staging + 3 MFMA quadrants, compiler-scheduled
        READ_A(cur, 0);
        READ_B2(cur, 0);
        STAGE_PAIR(nxt, k1, 1);
        STAGE_PAIR(nxt, k1, 2);
        STAGE_PAIR(nxt, k1, 3);
        __builtin_amdgcn_s_setprio(1); MFMA_Q(0, 0); __builtin_amdgcn_s_setprio(0);
        READ_B2(cur, 1);
        __builtin_amdgcn_s_setprio(1); MFMA_Q(0, 1); __builtin_amdgcn_s_setprio(0);
        READ_A(cur, 1);
        __builtin_amdgcn_s_setprio(1); MFMA_Q(1, 0); __builtin_amdgcn_s_setprio(0);

        // all cur reads retired (lgkm=0) before any wave overwrites cur p0 below
        FENCE_LGKM; BAR;

        __builtin_amdgcn_s_setprio(1); MFMA_Q(1, 1); __builtin_amdgcn_s_setprio(0);
        STAGE_PAIR(cur, k2, 0);   // tau+2 p0 into rows 0-63 (disjoint from pending row-64+ reads)
        WAIT_VM2; FENCE_LGKM; BAR;  // retires nxt p0..p3 (queue: [nxt p0..p3, cur p0])
    }
    asm volatile("s_waitcnt vmcnt(0)" ::: "memory");

    // epilogue: C layout col=lane&15, row=(lane>>4)*4+reg
#pragma unroll
    for (int mi = 0; mi < 8; mi++)
#pragma unroll
        for (int ni = 0; ni < 4; ni++) {
            const int row = brow + wr * 128 + mi * 16 + kq * 4;
            const int col = bcol + wc * 64 + ni * 16 + fr;
#pragma unroll
            for (int r = 0; r < 4; r++)
                C[(size_t)(row + r) * N + col] = (CT)acc[mi][ni][r];
        }
#undef STAGE_PAIR
#undef READ_A
#undef READ_B2
#undef MFMA_Q
#undef FENCE_LGKM
#undef WAIT_VM2
#undef BAR
}

// ---------------- MFMA phi_k + kv/ksum partials; T14 register prefetch of next tile's k/v ----------------
// k/v/q interleaved in kvq: row stride 3072, k at +0, v at +1024. LDS 42KB.
__global__ __launch_bounds__(256) void kv_kernel4(const _Float16* __restrict__ kvq,
                                                  const int* __restrict__ mask,
                                                  const _Float16* __restrict__ Phf,
                                                  float* __restrict__ kvpart,
                                                  float* __restrict__ kspart) {
    const int bh = blockIdx.y, b = bh >> 4, h = bh & 15;
    const int ch = blockIdx.x;
    const int t = threadIdx.x, lane = t & 63, w = t >> 6;
    const int fr = lane & 15, kq = lane >> 4;

    __shared__ _Float16 phis[256 * 64];   // [m][l] swizzled          32KB
    __shared__ _Float16 vst[80 * 64];     // [d][l] swizzled; row64=1 10KB

    if (t < 128) {
        const int row = 64 + (t >> 3), off = (t & 7) * 8;
        const _Float16 val = (row == 64) ? (_Float16)1.0f : (_Float16)0.0f;
        f16x8 o = {val, val, val, val, val, val, val, val};
        *(f16x8*)&vst[row * 64 + off] = o;
    }
    __syncthreads();

    f32x4 acc[4][5];
#pragma unroll
    for (int mf = 0; mf < 4; mf++)
#pragma unroll
        for (int n2 = 0; n2 < 5; n2++) acc[mf][n2] = (f32x4){0.f, 0.f, 0.f, 0.f};

    const int rr = t & 31, seg = t >> 5;
    const int NT = LC / 64;

    // T14: preload tile 0's k/v into registers
    f16x8 pv0, pv1, pk0, pk1;
    {
        const int l0 = ch * LC;
        const _Float16* v0 = kvq + (size_t)(b * L + l0 + 2 * rr) * KVQS + 1024 + h * DK + seg * 8;
        pv0 = *(const f16x8*)v0;
        pv1 = *(const f16x8*)(v0 + KVQS);
        const _Float16* krow = kvq + (size_t)(b * L + l0 + w * 16 + fr) * KVQS + h * DK + kq * 8;
        pk0 = *(const f16x8*)krow;
        pk1 = *(const f16x8*)(krow + 32);
    }

    for (int tile = 0; tile < NT; ++tile) {
        const int l0 = ch * LC + tile * 64;

        // consume current registers
        f16x8 va0 = pv0, va1 = pv1;
        f16x8 ak0 = pk0, ak1 = pk1;

        // issue next tile's loads immediately (clamped to tile 0; values unused on last iter)
        {
            const int ln = ch * LC + ((tile + 1 < NT) ? (tile + 1) * 64 : 0);
            const _Float16* v0 = kvq + (size_t)(b * L + ln + 2 * rr) * KVQS + 1024 + h * DK + seg * 8;
            pv0 = *(const f16x8*)v0;
            pv1 = *(const f16x8*)(v0 + KVQS);
            const _Float16* krow = kvq + (size_t)(b * L + ln + w * 16 + fr) * KVQS + h * DK + kq * 8;
            pk0 = *(const f16x8*)krow;
            pk1 = *(const f16x8*)(krow + 32);
        }

        // stage v transposed into vst (from current regs)
#pragma unroll
        for (int j = 0; j < 8; j++) {
            const int d = seg * 8 + j;
            f16x2 pk = {va0[j], va1[j]};
            *(f16x2*)&vst[SWZ(d, 2 * rr)] = pk;
        }

        float ns = 0.f;
#pragma unroll
        for (int j = 0; j < 8; j++)
            ns += (float)ak0[j] * (float)ak0[j] + (float)ak1[j] * (float)ak1[j];
        ns += __shfl_xor(ns, 16);
        ns += __shfl_xor(ns, 32);
        ns *= HALF_DN2;

        f32x4 pr[16];
#pragma unroll
        for (int nf = 0; nf < 16; nf++) {
            f16x8 b0 = *(const f16x8*)&Phf[((size_t)(nf * 2 + 0) * 64 + lane) * 8];
            f16x8 b1 = *(const f16x8*)&Phf[((size_t)(nf * 2 + 1) * 64 + lane) * 8];
            f32x4 c = {0.f, 0.f, 0.f, 0.f};
            c = __builtin_amdgcn_mfma_f32_16x16x32_f16(ak0, b0, c, 0, 0, 0);
            c = __builtin_amdgcn_mfma_f32_16x16x32_f16(ak1, b1, c, 0, 0, 0);
            pr[nf] = c;
        }
        float mx[4] = {-1e30f, -1e30f, -1e30f, -1e30f};
#pragma unroll
        for (int nf = 0; nf < 16; nf++)
#pragma unroll
            for (int r = 0; r < 4; r++) {
                pr[nf][r] *= DNORM;
                mx[r] = fmaxf(mx[r], pr[nf][r]);
            }
#pragma unroll
        for (int r = 0; r < 4; r++) {
            mx[r] = fmaxf(mx[r], __shfl_xor(mx[r], 1));
            mx[r] = fmaxf(mx[r], __shfl_xor(mx[r], 2));
            mx[r] = fmaxf(mx[r], __shfl_xor(mx[r], 4));
            mx[r] = fmaxf(mx[r], __shfl_xor(mx[r], 8));
        }
        float sub[4], mkv[4];
#pragma unroll
        for (int r = 0; r < 4; r++) {
            sub[r] = mx[r] + __shfl(ns, kq * 4 + r);
            mkv[r] = (float)mask[b * L + l0 + w * 16 + kq * 4 + r];
        }
#pragma unroll
        for (int nf = 0; nf < 16; nf++) {
            const int col = nf * 16 + fr;
#pragma unroll
            for (int rp = 0; rp < 2; rp++) {
                const int row = w * 16 + kq * 4 + 2 * rp;
                float v0 = mkv[2 * rp]     * (RATIO * (__expf(pr[nf][2 * rp]     - sub[2 * rp])     + 1e-6f));
                float v1 = mkv[2 * rp + 1] * (RATIO * (__expf(pr[nf][2 * rp + 1] - sub[2 * rp + 1]) + 1e-6f));
                f16x2 pk = {(_Float16)v0, (_Float16)v1};
                *(f16x2*)&phis[SWZ(col, row)] = pk;
            }
        }
        __syncthreads();

        f16x8 bfr[5][2];
#pragma unroll
        for (int n2 = 0; n2 < 5; n2++)
#pragma unroll
            for (int ks = 0; ks < 2; ks++)
                bfr[n2][ks] = *(const f16x8*)&vst[SWZ(n2 * 16 + fr, ks * 32 + kq * 8)];
#pragma unroll
        for (int mf = 0; mf < 4; mf++) {
            const int m = w * 64 + mf * 16 + fr;
            f16x8 a0 = *(const f16x8*)&phis[SWZ(m, kq * 8)];
            f16x8 a1 = *(const f16x8*)&phis[SWZ(m, 32 + kq * 8)];
#pragma unroll
            for (int n2 = 0; n2 < 5; n2++) {
                acc[mf][n2] = __builtin_amdgcn_mfma_f32_16x16x32_f16(a0, bfr[n2][0], acc[mf][n2], 0, 0, 0);
                acc[mf][n2] = __builtin_amdgcn_mfma_f32_16x16x32_f16(a1, bfr[n2][1], acc[mf][n2], 0, 0, 0);
            }
        }
        __syncthreads();
    }

    float* kvp = kvpart + ((size_t)ch * 64 + bh) * M * DK;
    float* ksp = kspart + ((size_t)ch * 64 + bh) * M;
#pragma unroll
    for (int mf = 0; mf < 4; mf++) {
#pragma unroll
        for (int r = 0; r < 4; r++) {
            const int m = w * 64 + mf * 16 + kq * 4 + r;
#pragma unroll
            for (int n2 = 0; n2 < 4; n2++)
                kvp[(size_t)m * DK + n2 * 16 + fr] = acc[mf][n2][r];
            if (fr == 0) ksp[m] = acc[mf][4][r];
        }
    }
}

// ---------------- reduce partials -> kvt fp16 FRAGMENT-LINEAR ----------------
__global__ __launch_bounds__(256) void reduce_kvt2(const float* __restrict__ kvp,
                                                   const float* __restrict__ ksp,
                                                   _Float16* __restrict__ kvt) {
    const int dq = blockIdx.x, bh = blockIdx.y;
    const int t  = threadIdx.x;   // m index
    float s[16];
#pragma unroll
    for (int c = 0; c < 16; c++) s[c] = 0.f;
    for (int ch = 0; ch < NCH; ch++) {
        const float* src = kvp + (((size_t)ch * 64 + bh) * M + t) * DK + dq * 16;
#pragma unroll
        for (int c4 = 0; c4 < 4; c4++) {
            float4 v = *(const float4*)(src + c4 * 4);
            s[c4 * 4 + 0] += v.x; s[c4 * 4 + 1] += v.y;
            s[c4 * 4 + 2] += v.z; s[c4 * 4 + 3] += v.w;
        }
    }
    _Float16* dst = kvt + (size_t)bh * 20480;
    const int ks = t >> 5, kq = (t >> 3) & 3, j = t & 7;
#pragma unroll
    for (int c = 0; c < 16; c++)
        dst[((dq * 8 + ks) * 64 + kq * 16 + c) * 8 + j] = (_Float16)s[c];
    if (dq == 0) {
        float s64 = 0.f;
        for (int ch = 0; ch < NCH; ch++) s64 += ksp[((size_t)ch * 64 + bh) * M + t];
        dst[((4 * 8 + ks) * 64 + kq * 16 + 0) * 8 + j] = (_Float16)s64;
#pragma unroll
        for (int c = 1; c < 16; c++)
            dst[((4 * 8 + ks) * 64 + kq * 16 + c) * 8 + j] = (_Float16)0.f;
    }
}

// ---------------- phi_q + out + denom + normalize; swapped QK, register butterfly ----------------
// q = kvq + 2048 (row stride KVQS). grid (L/64, B*H) = 4096 blocks, bijective XCD swizzle.
__global__ __launch_bounds__(256) void out_kernel8(const _Float16* __restrict__ q,
                                                   const _Float16* __restrict__ Phf,
                                                   const _Float16* __restrict__ kvtf,
                                                   _Float16* __restrict__ ao) {
    const int nwg = gridDim.x * gridDim.y;               // 4096
    int lid = blockIdx.y * gridDim.x + blockIdx.x;
    lid = (lid & 7) * (nwg >> 3) + (lid >> 3);           // bijective XCD chunking
    const int bh = lid >> 6, lblk = lid & 63;
    const int b = bh >> 4, h = bh & 15;
    const int l0 = lblk * 64;
    const int t = threadIdx.x, lane = t & 63, w = t >> 6;
    const int fr = lane & 15, kq = lane >> 4;

    __shared__ _Float16 kvs[2560 * 8];    // fragment-linear kvt  40KB

    {
        const _Float16* src = kvtf + (size_t)bh * 20480 + t * 8;
#pragma unroll
        for (int i = 0; i < 10; i++)
            gload16(src + i * 2048, kvs + t * 8 + i * 2048);
    }

    const int srcA = fr + 16 * ((2 * kq) & 3);
    const int srcB = fr + 16 * ((2 * kq + 1) & 3);
    const bool hi  = (kq & 2) != 0;

    const _Float16* qp = q + (size_t)(b * L + l0 + w * 16 + fr) * KVQS + h * DK + kq * 8;
    f16x8 aq0 = *(const f16x8*)qp;
    f16x8 aq1 = *(const f16x8*)(qp + 32);
    float ns = 0.f;
#pragma unroll
    for (int j = 0; j < 8; j++)
        ns += (float)aq0[j] * (float)aq0[j] + (float)aq1[j] * (float)aq1[j];
    ns += __shfl_xor(ns, 16);
    ns += __shfl_xor(ns, 32);
    ns *= HALF_DN2;

    f32x4 pr[16];
#pragma unroll
    for (int nf = 0; nf < 16; nf++) {
        f16x8 a0 = *(const f16x8*)&Phf[((size_t)(nf * 2 + 0) * 64 + lane) * 8];
        f16x8 a1 = *(const f16x8*)&Phf[((size_t)(nf * 2 + 1) * 64 + lane) * 8];
        f32x4 c = {0.f, 0.f, 0.f, 0.f};
        c = __builtin_amdgcn_mfma_f32_16x16x32_f16(a0, aq0, c, 0, 0, 0);
        c = __builtin_amdgcn_mfma_f32_16x16x32_f16(a1, aq1, c, 0, 0, 0);
        pr[nf] = c;
    }
    float mx = -1e30f;
#pragma unroll
    for (int nf = 0; nf < 16; nf++)
#pragma unroll
        for (int r = 0; r < 4; r++) {
            pr[nf][r] *= DNORM;
            mx = fmaxf(mx, pr[nf][r]);
        }
    mx = fmaxf(mx, __shfl_xor(mx, 16));
    mx = fmaxf(mx, __shfl_xor(mx, 32));
    const float sub = mx + ns;

    unsigned pk_[16][2];
#pragma unroll
    for (int nf = 0; nf < 16; nf++) {
#pragma unroll
        for (int p = 0; p < 2; p++) {
            float v0 = RATIO * (__expf(pr[nf][2 * p]     - sub) + 1e-6f);
            float v1 = RATIO * (__expf(pr[nf][2 * p + 1] - sub) + 1e-6f);
            f16x2 pq = {(_Float16)v0, (_Float16)v1};
            pk_[nf][p] = __builtin_bit_cast(unsigned, pq);
        }
    }
    __syncthreads();   // kvs staged (drains vmcnt; hidden under phase 1)

    f32x4 acc[5];
#pragma unroll
    for (int n2 = 0; n2 < 5; n2++) acc[n2] = (f32x4){0.f, 0.f, 0.f, 0.f};
#pragma unroll
    for (int ks = 0; ks < 8; ks++) {
        unsigned u0 = __shfl(pk_[2 * ks][0], srcA);
        unsigned u1 = __shfl(pk_[2 * ks][1], srcA);
        unsigned u2 = __shfl(pk_[2 * ks][0], srcB);
        unsigned u3 = __shfl(pk_[2 * ks][1], srcB);
        unsigned v0 = __shfl(pk_[2 * ks + 1][0], srcA);
        unsigned v1 = __shfl(pk_[2 * ks + 1][1], srcA);
        unsigned v2 = __shfl(pk_[2 * ks + 1][0], srcB);
        unsigned v3 = __shfl(pk_[2 * ks + 1][1], srcB);
        u32x4 wv;
        wv[0] = hi ? v0 : u0;
        wv[1] = hi ? v1 : u1;
        wv[2] = hi ? v2 : u2;
        wv[3] = hi ? v3 : u3;
        f16x8 af = __builtin_bit_cast(f16x8, wv);
#pragma unroll
        for (int n2 = 0; n2 < 5; n2++) {
            f16x8 bfv = *(const f16x8*)&kvs[((n2 * 8 + ks) * 64 + lane) * 8];
            acc[n2] = __builtin_amdgcn_mfma_f32_16x16x32_f16(af, bfv, acc[n2], 0, 0, 0);
        }
    }
#pragma unroll
    for (int r = 0; r < 4; r++) {
        float den = __shfl(acc[4][r], (lane & 48));
        float inv = 1.f / fmaxf(den, 1e-6f);
        const int row = l0 + w * 16 + kq * 4 + r;
        _Float16* dst = ao + (size_t)(b * L + row) * D + h * DK;
#pragma unroll
        for (int n2 = 0; n2 < 4; n2++)
            dst[n2 * 16 + fr] = (_Float16)(acc[n2][r] * inv);
    }
}

extern "C" void kernel_launch(void* const* d_in, const int* in_sizes, int n_in,
                              void* d_out, int out_size, void* d_ws, size_t ws_size,
                              hipStream_t stream) {
    (void)in_sizes; (void)n_in; (void)out_size; (void)ws_size;
    const float* X    = (const float*)d_in[0];
    const int*   mask = (const int*)d_in[1];
    const float* Wq   = (const float*)d_in[2];
    const float* Wk   = (const float*)d_in[3];
    const float* Wv   = (const float*)d_in[4];
    const float* Wo   = (const float*)d_in[5];
    const float* P    = (const float*)d_in[6];

    char* ws = (char*)d_ws;
    // slot0 (32MB) serially hosts Xh -> kvpart -> attn (lifetimes disjoint by kernel order)
    _Float16* Xh    = (_Float16*)ws;                      // castX..gemmKVQ
    float* kvpart   = (float*)ws;                         // kv_kernel4..reduce
    _Float16* attn  = (_Float16*)ws;                      // out_kernel8..gemmO
    _Float16* kvq   = (_Float16*)(ws + 33554432);         // 96MB [k|v|q] stride 3072
    float* kspart   = (float*)(ws + 134217728);           // 512KB
    _Float16* kvt   = (_Float16*)(ws + 134742016);        // 2.62MB
    _Float16* Wall  = (_Float16*)(ws + 137363456);        // 8MB [Wk;Wv;Wq;Wo]
    _Float16* Phf   = (_Float16*)(ws + 145752064);        // 32KB -> extent 145.8MB (proven)
    float* out      = (float*)d_out;

    dim3 blk(256);
    hipLaunchKernelGGL(cast_all, dim3(10241), blk, 0, stream, X, Wk, Wv, Wq, Wo, P, Xh, Wall, Phf);

    // Fused K+V+Q projection: C[16384][3072] = Xh @ [Wk;Wv;Wq]^T
    hipLaunchKernelGGL((gemm256<_Float16>), dim3(12, 64), dim3(512), 0, stream, Xh, Wall, kvq, KVQS, D);

    hipLaunchKernelGGL(kv_kernel4, dim3(NCH, B * H), blk, 0, stream, kvq, mask, Phf, kvpart, kspart);
    hipLaunchKernelGGL(reduce_kvt2, dim3(4, 64), blk, 0, stream, kvpart, kspart, kvt);

    hipLaunchKernelGGL(out_kernel8, dim3(L / 64, B * H), blk, 0, stream, kvq + 2048, Phf, kvt, attn);

    hipLaunchKernelGGL((gemm256<float>), dim3(4, 64), dim3(512), 0, stream, attn, Wall + 3 * 1048576, out, D, D);
}